// Round 6
// baseline (97.503 us; speedup 1.0000x reference)
//
#include <hip/hip_runtime.h>

typedef __attribute__((ext_vector_type(4))) float  f4;
typedef __attribute__((ext_vector_type(2))) float  f2;
typedef __attribute__((ext_vector_type(8))) short  short8;
typedef __attribute__((ext_vector_type(4))) float  f32x4;
typedef __attribute__((ext_vector_type(2))) unsigned int u32x2;

static __device__ __forceinline__ unsigned short f2bf(float f) {
    unsigned u = __builtin_bit_cast(unsigned, f);
    unsigned r = (u + 0x7FFFu + ((u >> 16) & 1u)) >> 16;   // RNE
    return (unsigned short)r;
}
static __device__ __forceinline__ float bf2f(unsigned short h) {
    return __builtin_bit_cast(float, ((unsigned)h) << 16);
}

// ---------------- K0: WhT[d][c]=bf16(g*Wh[c][d]); gb=g*bh; WfgT hi/lo split ----------------
__global__ __launch_bounds__(256) void k_setup(const float* __restrict__ Wh,
                                               const float* __restrict__ bh,
                                               const float* __restrict__ Wf,
                                               const float* __restrict__ Wg,
                                               const float* __restrict__ gamma,
                                               unsigned short* __restrict__ WhT,
                                               float* __restrict__ gb,
                                               unsigned short* __restrict__ Wfg_hi,
                                               unsigned short* __restrict__ Wfg_lo) {
    __shared__ float T[8 * 260];
    const int t = threadIdx.x, b = blockIdx.x;
    const float g = gamma[0];
    if (b < 32) {
        const int c0 = b * 8;
        const int cr = t >> 5, q = t & 31;
        f4 v0 = *(const f4*)(Wh + (c0 + cr) * 256 + q * 8);
        f4 v1 = *(const f4*)(Wh + (c0 + cr) * 256 + q * 8 + 4);
        *(f4*)(T + cr * 260 + q * 8)     = v0;
        *(f4*)(T + cr * 260 + q * 8 + 4) = v1;
        __syncthreads();
        short8 o;
        #pragma unroll
        for (int j = 0; j < 8; ++j) o[j] = (short)f2bf(g * T[j * 260 + t]);
        *(short8*)(WhT + t * 256 + c0) = o;
    } else {
        gb[t] = g * bh[t];
        const int n = t >> 2, cq = t & 3;
        const float* Wsrc = (n < 32) ? Wf : Wg;
        const int nn = n & 31;
        #pragma unroll
        for (int c8 = 0; c8 < 8; ++c8) {
            short8 h8, l8;
            #pragma unroll
            for (int k = 0; k < 8; ++k) {
                const int c = cq * 64 + c8 * 8 + k;
                const float v = Wsrc[c * 32 + nn];
                const unsigned short h = f2bf(v);
                h8[k] = (short)h;
                l8[k] = (short)f2bf(v - bf2f(h));
            }
            *(short8*)(Wfg_hi + n * 256 + cq * 64 + c8 * 8) = h8;
            *(short8*)(Wfg_lo + n * 256 + cq * 64 + c8 * 8) = l8;
        }
    }
}

// ---------------- KA: f,g via split-bf16 MFMA + partial s (fp32) ----------------
// 1024 blocks x 256 thr (4 waves). Block: 4 pixels x 16 batches = 64 rows, K=256, N=64 (f|g).
__global__ __launch_bounds__(256, 2) void ka(const float* __restrict__ x,
                                             const unsigned short* __restrict__ Wfg_hi,
                                             const unsigned short* __restrict__ Wfg_lo,
                                             const float* __restrict__ bfv,
                                             const float* __restrict__ bgv,
                                             float* __restrict__ s_part) {
    __shared__ __align__(16) unsigned char smem[65536];   // xhi [0,32K), xlo [32K,64K)

    const int t = threadIdx.x, w = t >> 6, l = t & 63;
    const int p = blockIdx.x * 4 + w;      // pixel per wave

    // ---- stage x tile as bf16 hi/lo, XOR-swizzled rows ----
    f4 xr[16];
    #pragma unroll
    for (int j = 0; j < 16; ++j)
        xr[j] = *(const f4*)(x + (((j << 12) + p) << 8) + l * 4);
    #pragma unroll
    for (int j = 0; j < 16; ++j) {
        const int r = j * 4 + w;
        int bo = r * 512 + l * 8;
        bo ^= (r & 7) << 4;
        const unsigned short h0 = f2bf(xr[j][0]), h1 = f2bf(xr[j][1]);
        const unsigned short h2 = f2bf(xr[j][2]), h3 = f2bf(xr[j][3]);
        u32x2 ph, pl;
        ph[0] = ((unsigned)h1 << 16) | h0;
        ph[1] = ((unsigned)h3 << 16) | h2;
        const unsigned short e0 = f2bf(xr[j][0] - bf2f(h0));
        const unsigned short e1 = f2bf(xr[j][1] - bf2f(h1));
        const unsigned short e2 = f2bf(xr[j][2] - bf2f(h2));
        const unsigned short e3 = f2bf(xr[j][3] - bf2f(h3));
        pl[0] = ((unsigned)e1 << 16) | e0;
        pl[1] = ((unsigned)e3 << 16) | e2;
        *(u32x2*)(smem + bo)         = ph;
        *(u32x2*)(smem + 32768 + bo) = pl;
    }
    __syncthreads();

    // ---- MFMA: wave owns 16 N-cols (ncol); 3-term split correction ----
    const int lrow = l & 15;
    const int kfe  = (l >> 4) * 8;
    const int ncol = w * 16 + lrow;
    f32x4 acc[4];
    #pragma unroll
    for (int mt = 0; mt < 4; ++mt) acc[mt] = (f32x4){0.f, 0.f, 0.f, 0.f};

    #pragma unroll
    for (int k0 = 0; k0 < 256; k0 += 32) {
        const short8 bh_ = *(const short8*)(Wfg_hi + ncol * 256 + k0 + kfe);
        const short8 bl_ = *(const short8*)(Wfg_lo + ncol * 256 + k0 + kfe);
        short8 ah[4], al[4];
        #pragma unroll
        for (int mt = 0; mt < 4; ++mt) {
            const int row = mt * 16 + lrow;
            int bo = row * 512 + (k0 + kfe) * 2;
            bo ^= (row & 7) << 4;
            ah[mt] = *(const short8*)(smem + bo);
            al[mt] = *(const short8*)(smem + 32768 + bo);
        }
        #pragma unroll
        for (int mt = 0; mt < 4; ++mt) {
            acc[mt] = __builtin_amdgcn_mfma_f32_16x16x32_bf16(ah[mt], bh_, acc[mt], 0, 0, 0);
            acc[mt] = __builtin_amdgcn_mfma_f32_16x16x32_bf16(al[mt], bh_, acc[mt], 0, 0, 0);
            acc[mt] = __builtin_amdgcn_mfma_f32_16x16x32_bf16(ah[mt], bl_, acc[mt], 0, 0, 0);
        }
    }
    __syncthreads();

    // ---- write F/G (+bias) to LDS (aliases xhi), stride 68 floats ----
    float* FG = (float*)smem;
    const float bias = (ncol < 32) ? bfv[ncol] : bgv[ncol - 32];
    #pragma unroll
    for (int mt = 0; mt < 4; ++mt)
        #pragma unroll
        for (int jj = 0; jj < 4; ++jj) {
            const int row = mt * 16 + (l >> 4) * 4 + jj;
            FG[row * 68 + ncol] = acc[mt][jj] + bias;
        }
    __syncthreads();

    // ---- partial s[i][j] over this block's 4 pixels (fp32) ----
    const int si = t >> 4, sj = t & 15;
    float sacc = 0.f;
    #pragma unroll
    for (int q = 0; q < 4; ++q) {
        const float* Gp = FG + (si * 4 + q) * 68 + 32;
        const float* Fp = FG + (sj * 4 + q) * 68;
        #pragma unroll
        for (int d4 = 0; d4 < 8; ++d4) {
            f4 gv = *(const f4*)(Gp + d4 * 4);
            f4 fv = *(const f4*)(Fp + d4 * 4);
            sacc += gv[0] * fv[0] + gv[1] * fv[1] + gv[2] * fv[2] + gv[3] * fv[3];
        }
    }
    s_part[blockIdx.x * 256 + si * 16 + sj] = sacc;
}

// ---------------- KB1: parallel reduce 1024 partials -> 64 ----------------
__global__ __launch_bounds__(256) void kb1(const float* __restrict__ s_part,
                                           float* __restrict__ s_red) {
    const int t = threadIdx.x, b = blockIdx.x;
    float a = 0.f;
    #pragma unroll
    for (int k = 0; k < 16; ++k) a += s_part[(b * 16 + k) * 256 + t];
    s_red[b * 256 + t] = a;
}

// ---------------- KB2: reduce 64 partials + softmax -> beta ----------------
__global__ __launch_bounds__(1024) void kb2(const float* __restrict__ s_red,
                                            float* __restrict__ beta) {
    __shared__ float red[4 * 256];
    __shared__ float srow[256];
    __shared__ float erow[256];
    const int t = threadIdx.x;
    const int pair = t & 255;
    const int qr = t >> 8;       // 0..3
    float a = 0.f;
    #pragma unroll
    for (int b = qr * 16; b < qr * 16 + 16; ++b) a += s_red[b * 256 + pair];
    red[qr * 256 + pair] = a;
    __syncthreads();
    float s = 0.f, e = 0.f;
    if (t < 256) {
        s = red[pair] + red[256 + pair] + red[512 + pair] + red[768 + pair];
        srow[pair] = s;
    }
    __syncthreads();
    if (t < 256) {
        const int i = pair >> 4;
        float m = srow[i * 16];
        #pragma unroll
        for (int j = 1; j < 16; ++j) m = fmaxf(m, srow[i * 16 + j]);
        e = expf(s - m);
        erow[pair] = e;
    }
    __syncthreads();
    if (t < 256) {
        const int i = pair >> 4;
        float sum = 0.f;
        #pragma unroll
        for (int j = 0; j < 16; ++j) sum += erow[i * 16 + j];
        beta[pair] = e / sum;
    }
}

// ---------------- KC: mix (beta @ x) + GEMM(bf16 MFMA) + residual ----------------
// grid 2048 x 256 threads (4 waves). 2 pixels/block. M = 32 rows (r = i*2 + px).
// Mix: thread owns (px = w>>1, 2 channels); GEMM: wave owns 64 N-cols, all 32 M-rows.
// Epilogue: LDS-transpose per 16-row half; residual = vectorized f4 x re-read (L3-hit).
__global__ __launch_bounds__(256, 5) void kc(const float* __restrict__ x,
                                             const unsigned short* __restrict__ WhT,
                                             const float* __restrict__ gb,
                                             const float* __restrict__ beta,
                                             float* __restrict__ out) {
    __shared__ __align__(16) unsigned char smem[16896];   // stage 16384 B / cst 16512 B (aliased)

    const int t = threadIdx.x;
    const int w = t >> 6;
    const int l = t & 63;
    const int p0 = blockIdx.x * 2;

    // ---- mixing: xm[r=i*2+px][cb2..cb2+1] = sum_j beta[i][j] * x[j][p0+px][c] ----
    {
        const int px  = w >> 1;
        const int cb2 = ((w & 1) * 64 + l) * 2;     // 2-channel column base
        const int p   = p0 + px;
        f2 xr[16];
        #pragma unroll
        for (int j = 0; j < 16; ++j)
            xr[j] = *(const f2*)(x + (((j << 12) + p) << 8) + cb2);
        #pragma unroll
        for (int i = 0; i < 16; ++i) {
            f2 a = {0.f, 0.f};
            #pragma unroll
            for (int j = 0; j < 16; ++j) {
                const float bij = beta[i * 16 + j];   // wave-uniform -> s_load
                a += xr[j] * bij;
            }
            const int r = i * 2 + px;
            int bo = r * 512 + cb2 * 2;
            bo ^= (r & 7) << 4;                       // XOR swizzle (T2)
            *(unsigned*)(smem + bo) = ((unsigned)f2bf(a[1]) << 16) | f2bf(a[0]);
        }
    }
    __syncthreads();

    // ---- GEMM: [32 x 256(k)] @ WhT -> wave owns 64 cols ----
    f32x4 acc[2][4];
    #pragma unroll
    for (int mt = 0; mt < 2; ++mt)
        #pragma unroll
        for (int nt = 0; nt < 4; ++nt) acc[mt][nt] = (f32x4){0.f, 0.f, 0.f, 0.f};

    const int n0 = w * 64;
    const int lrow = l & 15;
    const int hi4 = l >> 4;
    const int kf = hi4 * 8;
    #pragma unroll
    for (int k0 = 0; k0 < 256; k0 += 32) {
        short8 af[2], bfr[4];
        #pragma unroll
        for (int mt = 0; mt < 2; ++mt) {
            const int row = mt * 16 + lrow;
            int bo = row * 512 + (k0 + kf) * 2;
            bo ^= (row & 7) << 4;
            af[mt] = *(const short8*)(smem + bo);
        }
        #pragma unroll
        for (int nt = 0; nt < 4; ++nt) {
            const int d = n0 + nt * 16 + lrow;
            bfr[nt] = *(const short8*)(WhT + d * 256 + k0 + kf);
        }
        #pragma unroll
        for (int mt = 0; mt < 2; ++mt)
            #pragma unroll
            for (int nt = 0; nt < 4; ++nt)
                acc[mt][nt] = __builtin_amdgcn_mfma_f32_16x16x32_bf16(
                    af[mt], bfr[nt], acc[mt][nt], 0, 0, 0);
    }

    // ---- epilogue: per 16-row half, LDS-transpose; residual f4 x re-read; nt stores ----
    float* cst = (float*)smem;                 // [16][258]
    const f4 gb4 = *(const f4*)(gb + l * 4);
    #pragma unroll
    for (int h = 0; h < 2; ++h) {
        __syncthreads();
        #pragma unroll
        for (int nt = 0; nt < 4; ++nt)
            #pragma unroll
            for (int j = 0; j < 4; ++j)
                cst[(hi4 * 4 + j) * 258 + n0 + nt * 16 + lrow] = acc[h][nt][j];
        __syncthreads();
        #pragma unroll
        for (int rr = 0; rr < 4; ++rr) {
            const int rl = w * 4 + rr;          // local row 0..15
            const int rg = h * 16 + rl;         // global M row = i*2 + px
            const int i  = rg >> 1, pxe = rg & 1;
            const int idx = (((i << 12) + p0 + pxe) << 8) + l * 4;
            f4 o = *(const f4*)(cst + rl * 258 + l * 4);
            o += gb4 + *(const f4*)(x + idx);
            __builtin_nontemporal_store(o, (f4*)(out + idx));
        }
    }
}

extern "C" void kernel_launch(void* const* d_in, const int* in_sizes, int n_in,
                              void* d_out, int out_size, void* d_ws, size_t ws_size,
                              hipStream_t stream) {
    const float* x     = (const float*)d_in[0];
    const float* Wf    = (const float*)d_in[1];
    const float* Wg    = (const float*)d_in[2];
    const float* Wh    = (const float*)d_in[3];
    const float* bfv   = (const float*)d_in[4];
    const float* bgv   = (const float*)d_in[5];
    const float* bhv   = (const float*)d_in[6];
    const float* gamma = (const float*)d_in[7];
    float* out = (float*)d_out;

    char* ws = (char*)d_ws;
    unsigned short* WhT = (unsigned short*)ws;                 // 131072 B
    float* gb     = (float*)(ws + 131072);                     // 1024 B
    float* beta   = (float*)(ws + 132096);                     // 1024 B
    float* s_part = (float*)(ws + 133120);                     // 1024*256*4 = 1 MB
    unsigned short* Wfg_hi = (unsigned short*)(ws + 1181696);  // 32768 B
    unsigned short* Wfg_lo = (unsigned short*)(ws + 1214464);  // 32768 B
    // s_red reuses the Wfg region (dead after ka completes, rewritten by k_setup each call)
    float* s_red  = (float*)(ws + 1181696);                    // 64*256*4 = 65536 B

    k_setup<<<dim3(33), dim3(256), 0, stream>>>(Wh, bhv, Wf, Wg, gamma, WhT, gb, Wfg_hi, Wfg_lo);
    ka<<<dim3(1024), dim3(256), 0, stream>>>(x, Wfg_hi, Wfg_lo, bfv, bgv, s_part);
    kb1<<<dim3(64), dim3(256), 0, stream>>>(s_part, s_red);
    kb2<<<dim3(1), dim3(1024), 0, stream>>>(s_red, beta);
    kc<<<dim3(2048), dim3(256), 0, stream>>>(x, WhT, gb, beta, out);
}

// Round 7
// 79.813 us; speedup vs baseline: 1.2216x; 1.2216x over previous
//
#include <hip/hip_runtime.h>

typedef __attribute__((ext_vector_type(4))) float  f4;
typedef __attribute__((ext_vector_type(2))) float  f2;
typedef __attribute__((ext_vector_type(8))) short  short8;
typedef __attribute__((ext_vector_type(4))) float  f32x4;
typedef __attribute__((ext_vector_type(2))) unsigned int u32x2;

static __device__ __forceinline__ unsigned short f2bf(float f) {
    unsigned u = __builtin_bit_cast(unsigned, f);
    unsigned r = (u + 0x7FFFu + ((u >> 16) & 1u)) >> 16;   // RNE
    return (unsigned short)r;
}
static __device__ __forceinline__ float bf2f(unsigned short h) {
    return __builtin_bit_cast(float, ((unsigned)h) << 16);
}

// ---------------- K0: WhT[d][c]=bf16(g*Wh[c][d]); gb=g*bh; WfgT hi/lo split ----------------
__global__ __launch_bounds__(256) void k_setup(const float* __restrict__ Wh,
                                               const float* __restrict__ bh,
                                               const float* __restrict__ Wf,
                                               const float* __restrict__ Wg,
                                               const float* __restrict__ gamma,
                                               unsigned short* __restrict__ WhT,
                                               float* __restrict__ gb,
                                               unsigned short* __restrict__ Wfg_hi,
                                               unsigned short* __restrict__ Wfg_lo) {
    __shared__ float T[8 * 260];
    const int t = threadIdx.x, b = blockIdx.x;
    const float g = gamma[0];
    if (b < 32) {
        const int c0 = b * 8;
        const int cr = t >> 5, q = t & 31;
        f4 v0 = *(const f4*)(Wh + (c0 + cr) * 256 + q * 8);
        f4 v1 = *(const f4*)(Wh + (c0 + cr) * 256 + q * 8 + 4);
        *(f4*)(T + cr * 260 + q * 8)     = v0;
        *(f4*)(T + cr * 260 + q * 8 + 4) = v1;
        __syncthreads();
        short8 o;
        #pragma unroll
        for (int j = 0; j < 8; ++j) o[j] = (short)f2bf(g * T[j * 260 + t]);
        *(short8*)(WhT + t * 256 + c0) = o;
    } else {
        gb[t] = g * bh[t];
        const int n = t >> 2, cq = t & 3;
        const float* Wsrc = (n < 32) ? Wf : Wg;
        const int nn = n & 31;
        #pragma unroll
        for (int c8 = 0; c8 < 8; ++c8) {
            short8 h8, l8;
            #pragma unroll
            for (int k = 0; k < 8; ++k) {
                const int c = cq * 64 + c8 * 8 + k;
                const float v = Wsrc[c * 32 + nn];
                const unsigned short h = f2bf(v);
                h8[k] = (short)h;
                l8[k] = (short)f2bf(v - bf2f(h));
            }
            *(short8*)(Wfg_hi + n * 256 + cq * 64 + c8 * 8) = h8;
            *(short8*)(Wfg_lo + n * 256 + cq * 64 + c8 * 8) = l8;
        }
    }
}

// ---------------- KA: f,g via split-bf16 MFMA + partial s (fp32) ----------------
// 1024 blocks x 256 thr (4 waves). Block: 4 pixels x 16 batches = 64 rows, K=256, N=64 (f|g).
__global__ __launch_bounds__(256, 2) void ka(const float* __restrict__ x,
                                             const unsigned short* __restrict__ Wfg_hi,
                                             const unsigned short* __restrict__ Wfg_lo,
                                             const float* __restrict__ bfv,
                                             const float* __restrict__ bgv,
                                             float* __restrict__ s_part) {
    __shared__ __align__(16) unsigned char smem[65536];   // xhi [0,32K), xlo [32K,64K)

    const int t = threadIdx.x, w = t >> 6, l = t & 63;
    const int p = blockIdx.x * 4 + w;      // pixel per wave

    // ---- stage x tile as bf16 hi/lo, XOR-swizzled rows ----
    f4 xr[16];
    #pragma unroll
    for (int j = 0; j < 16; ++j)
        xr[j] = *(const f4*)(x + (((j << 12) + p) << 8) + l * 4);
    #pragma unroll
    for (int j = 0; j < 16; ++j) {
        const int r = j * 4 + w;
        int bo = r * 512 + l * 8;
        bo ^= (r & 7) << 4;
        const unsigned short h0 = f2bf(xr[j][0]), h1 = f2bf(xr[j][1]);
        const unsigned short h2 = f2bf(xr[j][2]), h3 = f2bf(xr[j][3]);
        u32x2 ph, pl;
        ph[0] = ((unsigned)h1 << 16) | h0;
        ph[1] = ((unsigned)h3 << 16) | h2;
        const unsigned short e0 = f2bf(xr[j][0] - bf2f(h0));
        const unsigned short e1 = f2bf(xr[j][1] - bf2f(h1));
        const unsigned short e2 = f2bf(xr[j][2] - bf2f(h2));
        const unsigned short e3 = f2bf(xr[j][3] - bf2f(h3));
        pl[0] = ((unsigned)e1 << 16) | e0;
        pl[1] = ((unsigned)e3 << 16) | e2;
        *(u32x2*)(smem + bo)         = ph;
        *(u32x2*)(smem + 32768 + bo) = pl;
    }
    __syncthreads();

    // ---- MFMA: wave owns 16 N-cols (ncol); 3-term split correction ----
    const int lrow = l & 15;
    const int kfe  = (l >> 4) * 8;
    const int ncol = w * 16 + lrow;
    f32x4 acc[4];
    #pragma unroll
    for (int mt = 0; mt < 4; ++mt) acc[mt] = (f32x4){0.f, 0.f, 0.f, 0.f};

    #pragma unroll
    for (int k0 = 0; k0 < 256; k0 += 32) {
        const short8 bh_ = *(const short8*)(Wfg_hi + ncol * 256 + k0 + kfe);
        const short8 bl_ = *(const short8*)(Wfg_lo + ncol * 256 + k0 + kfe);
        short8 ah[4], al[4];
        #pragma unroll
        for (int mt = 0; mt < 4; ++mt) {
            const int row = mt * 16 + lrow;
            int bo = row * 512 + (k0 + kfe) * 2;
            bo ^= (row & 7) << 4;
            ah[mt] = *(const short8*)(smem + bo);
            al[mt] = *(const short8*)(smem + 32768 + bo);
        }
        #pragma unroll
        for (int mt = 0; mt < 4; ++mt) {
            acc[mt] = __builtin_amdgcn_mfma_f32_16x16x32_bf16(ah[mt], bh_, acc[mt], 0, 0, 0);
            acc[mt] = __builtin_amdgcn_mfma_f32_16x16x32_bf16(al[mt], bh_, acc[mt], 0, 0, 0);
            acc[mt] = __builtin_amdgcn_mfma_f32_16x16x32_bf16(ah[mt], bl_, acc[mt], 0, 0, 0);
        }
    }
    __syncthreads();

    // ---- write F/G (+bias) to LDS (aliases xhi), stride 68 floats ----
    float* FG = (float*)smem;
    const float bias = (ncol < 32) ? bfv[ncol] : bgv[ncol - 32];
    #pragma unroll
    for (int mt = 0; mt < 4; ++mt)
        #pragma unroll
        for (int jj = 0; jj < 4; ++jj) {
            const int row = mt * 16 + (l >> 4) * 4 + jj;
            FG[row * 68 + ncol] = acc[mt][jj] + bias;
        }
    __syncthreads();

    // ---- partial s[i][j] over this block's 4 pixels (fp32) ----
    const int si = t >> 4, sj = t & 15;
    float sacc = 0.f;
    #pragma unroll
    for (int q = 0; q < 4; ++q) {
        const float* Gp = FG + (si * 4 + q) * 68 + 32;
        const float* Fp = FG + (sj * 4 + q) * 68;
        #pragma unroll
        for (int d4 = 0; d4 < 8; ++d4) {
            f4 gv = *(const f4*)(Gp + d4 * 4);
            f4 fv = *(const f4*)(Fp + d4 * 4);
            sacc += gv[0] * fv[0] + gv[1] * fv[1] + gv[2] * fv[2] + gv[3] * fv[3];
        }
    }
    s_part[blockIdx.x * 256 + si * 16 + sj] = sacc;
}

// ---------------- KB1: parallel reduce 1024 partials -> 64 ----------------
__global__ __launch_bounds__(256) void kb1(const float* __restrict__ s_part,
                                           float* __restrict__ s_red) {
    const int t = threadIdx.x, b = blockIdx.x;
    float a = 0.f;
    #pragma unroll
    for (int k = 0; k < 16; ++k) a += s_part[(b * 16 + k) * 256 + t];
    s_red[b * 256 + t] = a;
}

// ---------------- KB2: reduce 64 partials + softmax -> beta ----------------
__global__ __launch_bounds__(1024) void kb2(const float* __restrict__ s_red,
                                            float* __restrict__ beta) {
    __shared__ float red[4 * 256];
    __shared__ float srow[256];
    __shared__ float erow[256];
    const int t = threadIdx.x;
    const int pair = t & 255;
    const int qr = t >> 8;       // 0..3
    float a = 0.f;
    #pragma unroll
    for (int b = qr * 16; b < qr * 16 + 16; ++b) a += s_red[b * 256 + pair];
    red[qr * 256 + pair] = a;
    __syncthreads();
    float s = 0.f, e = 0.f;
    if (t < 256) {
        s = red[pair] + red[256 + pair] + red[512 + pair] + red[768 + pair];
        srow[pair] = s;
    }
    __syncthreads();
    if (t < 256) {
        const int i = pair >> 4;
        float m = srow[i * 16];
        #pragma unroll
        for (int j = 1; j < 16; ++j) m = fmaxf(m, srow[i * 16 + j]);
        e = expf(s - m);
        erow[pair] = e;
    }
    __syncthreads();
    if (t < 256) {
        const int i = pair >> 4;
        float sum = 0.f;
        #pragma unroll
        for (int j = 0; j < 16; ++j) sum += erow[i * 16 + j];
        beta[pair] = e / sum;
    }
}

// ---------------- KC: mix (beta @ x, beta in LDS) + GEMM (prefetched) + residual ----------------
// grid 1024 x 256 threads (4 waves). 4 pixels/block. M rows r = i*4 + q (q = wave).
// beta staged to LDS once (broadcast ds_reads in mix — no per-iter SMEM waits).
// GEMM k-loop double-buffers the WhT B-fragments (load k+1 before k's MFMAs).
// Epilogue: LDS-transpose (stride 258, 2-way free), f4 x re-read (L2/L3 hit), NT stores.
__global__ __launch_bounds__(256, 3) void kc(const float* __restrict__ x,
                                             const unsigned short* __restrict__ WhT,
                                             const float* __restrict__ gb,
                                             const float* __restrict__ beta,
                                             float* __restrict__ out) {
    __shared__ __align__(16) unsigned char smem[34048];  // stage 32768 / cst 33024 (alias) + beta 1024
    float* beta_l = (float*)(smem + 33024);

    const int t = threadIdx.x;
    const int w = t >> 6;          // wave id = pixel q
    const int l = t & 63;
    const int p0 = blockIdx.x * 4;
    const int p  = p0 + w;
    const int cbase = l * 4;

    // ---- stage beta to LDS (wave 0) while xr loads are issued ----
    f4 xr[16];
    #pragma unroll
    for (int j = 0; j < 16; ++j)
        xr[j] = *(const f4*)(x + (((j << 12) + p) << 8) + cbase);
    if (t < 64) *(f4*)(beta_l + t * 4) = *(const f4*)(beta + t * 4);
    __syncthreads();

    // ---- mixing: xm[r=i*4+w][cbase..+3] = sum_j beta[i][j] * x[j][p][c] ----
    #pragma unroll
    for (int i = 0; i < 16; ++i) {
        f4 bv0 = *(const f4*)(beta_l + i * 16);        // broadcast reads
        f4 bv1 = *(const f4*)(beta_l + i * 16 + 4);
        f4 bv2 = *(const f4*)(beta_l + i * 16 + 8);
        f4 bv3 = *(const f4*)(beta_l + i * 16 + 12);
        f4 a = {0.f, 0.f, 0.f, 0.f};
        #pragma unroll
        for (int j = 0; j < 4; ++j) {
            a += xr[j]      * bv0[j];
            a += xr[4 + j]  * bv1[j];
            a += xr[8 + j]  * bv2[j];
            a += xr[12 + j] * bv3[j];
        }
        const int r = i * 4 + w;
        int bo = r * 512 + l * 8;
        bo ^= (r & 7) << 4;                      // XOR swizzle (T2)
        u32x2 packed;
        packed[0] = ((unsigned)f2bf(a[1]) << 16) | f2bf(a[0]);
        packed[1] = ((unsigned)f2bf(a[3]) << 16) | f2bf(a[2]);
        *(u32x2*)(smem + bo) = packed;
    }
    __syncthreads();

    // ---- GEMM: [64 x 256(k)] @ WhT -> wave owns 64 cols; B double-buffered ----
    f32x4 acc[4][4];
    #pragma unroll
    for (int mt = 0; mt < 4; ++mt)
        #pragma unroll
        for (int nt = 0; nt < 4; ++nt) acc[mt][nt] = (f32x4){0.f, 0.f, 0.f, 0.f};

    const int n0 = w * 64;
    const int lrow = l & 15;
    const int hi = l >> 4;
    const int kf = hi * 8;
    const unsigned short* wbase = WhT + (n0 + lrow) * 256 + kf;

    short8 bcur[4], bnxt[4];
    #pragma unroll
    for (int nt = 0; nt < 4; ++nt)
        bcur[nt] = *(const short8*)(wbase + nt * 16 * 256);

    #pragma unroll
    for (int ks = 0; ks < 8; ++ks) {
        const int k0 = ks * 32;
        if (ks < 7) {
            #pragma unroll
            for (int nt = 0; nt < 4; ++nt)
                bnxt[nt] = *(const short8*)(wbase + nt * 16 * 256 + k0 + 32);
        }
        short8 af[4];
        #pragma unroll
        for (int mt = 0; mt < 4; ++mt) {
            const int row = mt * 16 + lrow;
            int bo = row * 512 + (k0 + kf) * 2;
            bo ^= (row & 7) << 4;
            af[mt] = *(const short8*)(smem + bo);
        }
        #pragma unroll
        for (int mt = 0; mt < 4; ++mt)
            #pragma unroll
            for (int nt = 0; nt < 4; ++nt)
                acc[mt][nt] = __builtin_amdgcn_mfma_f32_16x16x32_bf16(
                    af[mt], bcur[nt], acc[mt][nt], 0, 0, 0);
        #pragma unroll
        for (int nt = 0; nt < 4; ++nt) bcur[nt] = bnxt[nt];
    }

    // ---- epilogue: LDS-transpose C in 2 halves; f4 x re-read; NT f4 stores ----
    float* cst = (float*)smem;                 // [32][258]
    const f4 gb4 = *(const f4*)(gb + cbase);
    #pragma unroll
    for (int h = 0; h < 2; ++h) {
        __syncthreads();
        #pragma unroll
        for (int mt2 = 0; mt2 < 2; ++mt2) {
            const int mt = h * 2 + mt2;
            #pragma unroll
            for (int nt = 0; nt < 4; ++nt)
                #pragma unroll
                for (int j = 0; j < 4; ++j) {
                    const int rl = mt2 * 16 + hi * 4 + j;
                    cst[rl * 258 + n0 + nt * 16 + lrow] = acc[mt][nt][j];
                }
        }
        __syncthreads();
        #pragma unroll
        for (int rr = 0; rr < 8; ++rr) {
            const int rl = rr * 4 + w;          // local row 0..31
            const int rg = h * 32 + rl;         // global M row = i*4 + q
            const int i  = rg >> 2, q = rg & 3;
            const int idx = (((i << 12) + p0 + q) << 8) + cbase;
            f4 o = *(const f4*)(cst + rl * 258 + cbase);
            o += gb4 + *(const f4*)(x + idx);
            __builtin_nontemporal_store(o, (f4*)(out + idx));
        }
    }
}

extern "C" void kernel_launch(void* const* d_in, const int* in_sizes, int n_in,
                              void* d_out, int out_size, void* d_ws, size_t ws_size,
                              hipStream_t stream) {
    const float* x     = (const float*)d_in[0];
    const float* Wf    = (const float*)d_in[1];
    const float* Wg    = (const float*)d_in[2];
    const float* Wh    = (const float*)d_in[3];
    const float* bfv   = (const float*)d_in[4];
    const float* bgv   = (const float*)d_in[5];
    const float* bhv   = (const float*)d_in[6];
    const float* gamma = (const float*)d_in[7];
    float* out = (float*)d_out;

    char* ws = (char*)d_ws;
    unsigned short* WhT = (unsigned short*)ws;                 // 131072 B
    float* gb     = (float*)(ws + 131072);                     // 1024 B
    float* beta   = (float*)(ws + 132096);                     // 1024 B
    float* s_part = (float*)(ws + 133120);                     // 1024*256*4 = 1 MB
    unsigned short* Wfg_hi = (unsigned short*)(ws + 1181696);  // 32768 B
    unsigned short* Wfg_lo = (unsigned short*)(ws + 1214464);  // 32768 B
    // s_red reuses the Wfg region (dead after ka completes, rewritten by k_setup each call)
    float* s_red  = (float*)(ws + 1181696);                    // 64*256*4 = 65536 B

    k_setup<<<dim3(33), dim3(256), 0, stream>>>(Wh, bhv, Wf, Wg, gamma, WhT, gb, Wfg_hi, Wfg_lo);
    ka<<<dim3(1024), dim3(256), 0, stream>>>(x, Wfg_hi, Wfg_lo, bfv, bgv, s_part);
    kb1<<<dim3(64), dim3(256), 0, stream>>>(s_part, s_red);
    kb2<<<dim3(1), dim3(1024), 0, stream>>>(s_red, beta);
    kc<<<dim3(1024), dim3(256), 0, stream>>>(x, WhT, gb, beta, out);
}